// Round 3
// baseline (894.801 us; speedup 1.0000x reference)
//
#include <hip/hip_runtime.h>
#include <math.h>

#define LSEQ 2048
#define NB 2
#define HDIM 1024
#define NKV 128          // 2*HEAD_SIZE
#define MALL (NB*LSEQ)   // 4096
#define KSPLIT 8

typedef float v4f __attribute__((ext_vector_type(4)));

// ---------------- K1: seq_out partials = inputs @ Wp (K split in 8) --------
// grid (8, 64): x = split, y = m-tile. 256 threads, 64x128 tile (full N, A read
// once), micro 4m x 8n, K-chunk 32, 4 chunks per split. 2 blocks/CU.
__global__ __launch_bounds__(256) void k1_gemm(const float* __restrict__ A,
                                               const float* __restrict__ Wp,
                                               float* __restrict__ Cp) {
    const int split = blockIdx.x;
    const int m0 = blockIdx.y * 64;
    __shared__ float As[32][68];    // [k][m] transposed, pad 68
    __shared__ float Bs[32][128];   // [k][n]
    const int tid = threadIdx.x;
    const int tm = tid & 15;        // m quad: rows 4*tm..+3
    const int tn = tid >> 4;        // n octet: cols 8*tn..+7
    float acc[4][8] = {};
    for (int kc = 0; kc < 4; ++kc) {
        const int k0 = split*128 + kc*32;
        #pragma unroll
        for (int p = 0; p < 2; ++p) {
            int idx = tid + 256*p;          // 0..511
            int row = idx >> 3, kq = idx & 7;
            float4 a = *(const float4*)(A + (size_t)(m0+row)*HDIM + k0 + 4*kq);
            As[4*kq+0][row] = a.x;
            As[4*kq+1][row] = a.y;
            As[4*kq+2][row] = a.z;
            As[4*kq+3][row] = a.w;
        }
        #pragma unroll
        for (int p = 0; p < 4; ++p) {
            int idx = tid + 256*p;          // 0..1023 f4 slots
            int r = idx >> 5, c = idx & 31;
            *(float4*)(&Bs[r][4*c]) = *(const float4*)(Wp + (size_t)(k0+r)*NKV + 4*c);
        }
        __syncthreads();
        #pragma unroll
        for (int kk = 0; kk < 32; ++kk) {
            float4 av  = *(const float4*)(&As[kk][4*tm]);
            float4 bv0 = *(const float4*)(&Bs[kk][8*tn]);
            float4 bv1 = *(const float4*)(&Bs[kk][8*tn+4]);
            float aa[4] = {av.x, av.y, av.z, av.w};
            float bb[8] = {bv0.x, bv0.y, bv0.z, bv0.w, bv1.x, bv1.y, bv1.z, bv1.w};
            #pragma unroll
            for (int i = 0; i < 4; ++i)
                #pragma unroll
                for (int j = 0; j < 8; ++j)
                    acc[i][j] = fmaf(aa[i], bb[j], acc[i][j]);
        }
        __syncthreads();
    }
    float* outp = Cp + (size_t)split*MALL*NKV;
    #pragma unroll
    for (int i = 0; i < 4; ++i) {
        float* rp = outp + (size_t)(m0 + 4*tm + i)*NKV + 8*tn;
        *(float4*)(rp)     = make_float4(acc[i][0], acc[i][1], acc[i][2], acc[i][3]);
        *(float4*)(rp + 4) = make_float4(acc[i][4], acc[i][5], acc[i][6], acc[i][7]);
    }
}

// ---------------- K2: sum K-splits (+bp), RoPE, bias = seq@Wq/2 ------------
// grid 4096 blocks x 64 threads (1 wave per row).
__global__ __launch_bounds__(64) void k2_rope_bias(const float* __restrict__ Cp,
        const float* __restrict__ bp, const float* __restrict__ Wq,
        const float* __restrict__ bq, float* __restrict__ qwout,
        float* __restrict__ kwout, float* __restrict__ biasQ,
        float* __restrict__ biasK) {
    const int row = blockIdx.x;         // 0..4095 (b*L + l)
    const int b = row >> 11;
    const int l = row & (LSEQ - 1);
    const int t = threadIdx.x;          // 0..63 ; lane t owns dims (2t, 2t+1)
    float x0 = bp[2*t], x1 = bp[2*t+1];
    #pragma unroll
    for (int s = 0; s < KSPLIT; ++s) {
        const float2 v = *(const float2*)(Cp + ((size_t)s*MALL + row)*NKV + 2*t);
        x0 += v.x;
        x1 += v.y;
    }
    // RoPE: lanes 0..31 -> q (dims 0..63), lanes 32..63 -> k (dims 64..127)
    const int p = t & 31;               // pair index within head
    float inv = exp2f(-0.41524101186098287f * (float)p);  // 10000^(-p/32)
    float ang = (float)l * inv;
    float sn = sinf(ang), cs = cosf(ang);
    float y0 = x0*cs - x1*sn;
    float y1 = x1*cs + x0*sn;
    float* dst = (t < 32) ? (qwout + (size_t)row*64) : (kwout + (size_t)row*64);
    dst[2*p]   = y0;
    dst[2*p+1] = y1;
    // bias: 24 dot-products of (pre-RoPE) row with Wq columns, wave-reduced
    float res = 0.f;
    for (int j = 0; j < 24; ++j) {
        float part = fmaf(x0, Wq[(2*t)*24 + j], x1 * Wq[(2*t+1)*24 + j]);
        #pragma unroll
        for (int off = 32; off > 0; off >>= 1)
            part += __shfl_xor(part, off);
        if (t == j) res = part;
    }
    if (t < 24) {
        float v = (res + bq[t]) * 0.5f;
        int h = t >> 1;
        float* bb = (t & 1) ? biasK : biasQ;
        bb[((size_t)b*12 + h)*LSEQ + l] = v;
    }
}

// ---------------- K3 v5: scores + bias + mask + tril, 12-head fan-out ------
// grid (256, 2): x = m-tile (8 rows), y = b. 256 threads = 4 waves.
// Wave w owns m rows {2w, 2w+1}; lane l owns n-quad n = nb + 4l .. +3.
// kw chunk (256 n x 64 d) staged in LDS with rotation swizzle
// slot(r,q) = r*16 + ((q + r/4) & 15): even banks for BOTH the coalesced
// staging write and the per-lane 4-row b128 reads. Stores: float4
// nontemporal, 1 KB/wave-inst, bypassing L2 (out >> L3).
__global__ __launch_bounds__(256, 2) void k3_scores(const float* __restrict__ qw,
        const float* __restrict__ kwv, const float* __restrict__ biasQ,
        const float* __restrict__ biasK, const int* __restrict__ mask,
        float* __restrict__ out) {
    const int m0 = blockIdx.x * 8;
    const int b  = blockIdx.y;
    const int tid = threadIdx.x;
    const int l   = tid & 63;       // lane
    const int w   = tid >> 6;       // wave: rows 2w, 2w+1
    __shared__ float4 kws4[4096];   // 256 rows x 16 quads, swizzled (64 KB)

    const size_t rowbase = (size_t)b * LSEQ;
    const int mA = m0 + 2*w, mB = mA + 1;

    float4 q0[16], q1[16];
    {
        const float4* qp0 = (const float4*)(qw + (rowbase + mA)*64);
        const float4* qp1 = (const float4*)(qw + (rowbase + mB)*64);
        #pragma unroll
        for (int j = 0; j < 16; ++j) { q0[j] = qp0[j]; q1[j] = qp1[j]; }
    }
    float bq0[12], bq1[12];
    #pragma unroll
    for (int h = 0; h < 12; ++h) {
        const float* bqp = biasQ + ((size_t)b*12 + h)*LSEQ;
        bq0[h] = bqp[mA];
        bq1[h] = bqp[mB];
    }
    const bool okmA = mask[rowbase + mA] != 0;
    const bool okmB = mask[rowbase + mB] != 0;
    const size_t outbase = (size_t)b * 12 * LSEQ * LSEQ;
    const float4* kg = (const float4*)(kwv + rowbase*64);

    for (int c = 0; c < 8; ++c) {
        const int nb = c * 256;
        __syncthreads();                 // guard vs previous chunk's readers
        #pragma unroll 4
        for (int p = 0; p < 16; ++p) {
            int f4id = tid + 256*p;      // 0..4095
            int r = f4id >> 4, q = f4id & 15;
            float4 v = kg[(size_t)(nb + r)*16 + q];
            kws4[r*16 + ((q + (r >> 2)) & 15)] = v;
        }
        __syncthreads();

        float accA[4] = {}, accB[4] = {};
        #pragma unroll
        for (int j = 0; j < 16; ++j) {
            const int rot = (j + l) & 15;
            float4 k0v = kws4[(4*l + 0)*16 + rot];
            float4 k1v = kws4[(4*l + 1)*16 + rot];
            float4 k2v = kws4[(4*l + 2)*16 + rot];
            float4 k3v = kws4[(4*l + 3)*16 + rot];
            float4 qa = q0[j], qb = q1[j];
            accA[0] = fmaf(qa.x, k0v.x, accA[0]); accA[0] = fmaf(qa.y, k0v.y, accA[0]);
            accA[0] = fmaf(qa.z, k0v.z, accA[0]); accA[0] = fmaf(qa.w, k0v.w, accA[0]);
            accA[1] = fmaf(qa.x, k1v.x, accA[1]); accA[1] = fmaf(qa.y, k1v.y, accA[1]);
            accA[1] = fmaf(qa.z, k1v.z, accA[1]); accA[1] = fmaf(qa.w, k1v.w, accA[1]);
            accA[2] = fmaf(qa.x, k2v.x, accA[2]); accA[2] = fmaf(qa.y, k2v.y, accA[2]);
            accA[2] = fmaf(qa.z, k2v.z, accA[2]); accA[2] = fmaf(qa.w, k2v.w, accA[2]);
            accA[3] = fmaf(qa.x, k3v.x, accA[3]); accA[3] = fmaf(qa.y, k3v.y, accA[3]);
            accA[3] = fmaf(qa.z, k3v.z, accA[3]); accA[3] = fmaf(qa.w, k3v.w, accA[3]);
            accB[0] = fmaf(qb.x, k0v.x, accB[0]); accB[0] = fmaf(qb.y, k0v.y, accB[0]);
            accB[0] = fmaf(qb.z, k0v.z, accB[0]); accB[0] = fmaf(qb.w, k0v.w, accB[0]);
            accB[1] = fmaf(qb.x, k1v.x, accB[1]); accB[1] = fmaf(qb.y, k1v.y, accB[1]);
            accB[1] = fmaf(qb.z, k1v.z, accB[1]); accB[1] = fmaf(qb.w, k1v.w, accB[1]);
            accB[2] = fmaf(qb.x, k2v.x, accB[2]); accB[2] = fmaf(qb.y, k2v.y, accB[2]);
            accB[2] = fmaf(qb.z, k2v.z, accB[2]); accB[2] = fmaf(qb.w, k2v.w, accB[2]);
            accB[3] = fmaf(qb.x, k3v.x, accB[3]); accB[3] = fmaf(qb.y, k3v.y, accB[3]);
            accB[3] = fmaf(qb.z, k3v.z, accB[3]); accB[3] = fmaf(qb.w, k3v.w, accB[3]);
        }

        const int n0 = nb + 4*l;
        const int4 mv = *(const int4*)(mask + rowbase + n0);
        const int okn[4] = {mv.x != 0, mv.y != 0, mv.z != 0, mv.w != 0};
        float baseA[4], baseB[4];
        #pragma unroll
        for (int i = 0; i < 4; ++i) {
            const int n = n0 + i;
            baseA[i] = (okmA && okn[i]) ? (accA[i]*0.125f - ((mA > n) ? 1e12f : 0.f))
                                        : -INFINITY;
            baseB[i] = (okmB && okn[i]) ? (accB[i]*0.125f - ((mB > n) ? 1e12f : 0.f))
                                        : -INFINITY;
        }
        const float* bkbase = biasK + (size_t)b*12*LSEQ + n0;
        float* outA = out + outbase + (size_t)mA*LSEQ + n0;
        #pragma unroll
        for (int h = 0; h < 12; ++h) {
            float4 bk = *(const float4*)(bkbase + (size_t)h*LSEQ);
            v4f vA, vB;
            vA.x = baseA[0] + bq0[h] + bk.x;
            vA.y = baseA[1] + bq0[h] + bk.y;
            vA.z = baseA[2] + bq0[h] + bk.z;
            vA.w = baseA[3] + bq0[h] + bk.w;
            vB.x = baseB[0] + bq1[h] + bk.x;
            vB.y = baseB[1] + bq1[h] + bk.y;
            vB.z = baseB[2] + bq1[h] + bk.z;
            vB.w = baseB[3] + bq1[h] + bk.w;
            float* po = outA + (size_t)h*LSEQ*LSEQ;
            __builtin_nontemporal_store(vA, (v4f*)po);
            __builtin_nontemporal_store(vB, (v4f*)(po + LSEQ));
        }
    }
}

extern "C" void kernel_launch(void* const* d_in, const int* in_sizes, int n_in,
                              void* d_out, int out_size, void* d_ws, size_t ws_size,
                              hipStream_t stream) {
    const float* inputs = (const float*)d_in[0];   // (2,2048,1024)
    const int*   mask   = (const int*)  d_in[1];   // (2,2048)
    const float* Wp     = (const float*)d_in[2];   // (1024,128)
    const float* bp     = (const float*)d_in[3];   // (128,)
    const float* Wq     = (const float*)d_in[4];   // (128,24)
    const float* bq     = (const float*)d_in[5];   // (24,)
    float* out = (float*)d_out;                    // (2,12,2048,2048)

    float* Cp  = (float*)d_ws;                     // KSPLIT * 4096 * 128
    float* qwb = Cp  + (size_t)KSPLIT*MALL*NKV;    // 4096 * 64
    float* kwb = qwb + (size_t)MALL*64;            // 4096 * 64
    float* bQ  = kwb + (size_t)MALL*64;            // 2*12*2048
    float* bK  = bQ  + (size_t)NB*12*LSEQ;         // 2*12*2048

    k1_gemm     <<<dim3(KSPLIT, 64), 256, 0, stream>>>(inputs, Wp, Cp);
    k2_rope_bias<<<dim3(MALL),        64, 0, stream>>>(Cp, bp, Wq, bq, qwb, kwb, bQ, bK);
    k3_scores   <<<dim3(256, 2),     256, 0, stream>>>(qwb, kwb, bQ, bK, mask, out);
}